// Round 1
// baseline (71.762 us; speedup 1.0000x reference)
//
#include <hip/hip_runtime.h>
#include <hip/hip_bf16.h>
#include <stdint.h>

// Problem constants (fixed by setup_inputs)
#define KC   256      // concepts
#define BB   128      // batch
#define DD   256      // feature dim
#define MM   4        // protos per concept
#define NPROT 1024    // KC*MM
#define NQ   32768    // BB*KC

// ws layout (bytes). Total ~642 KB.
#define OFF_NSEL 0
#define OFF_SEL  256                      // int[32768]
#define OFF_PN   (256 + 131072)           // bf16 protos, swizzled, slab-major: [4 slabs][1024 rows][128B]
#define OFF_PART (OFF_PN + 4*1024*128)    // float[256] block partials

#define LN2F    0.69314718055994531f
#define C10L2E  14.426950408889634f       // 10 * log2(e)  (1/T folded into exp2 domain)

typedef __bf16 bf16x8 __attribute__((ext_vector_type(8)));
typedef float  f32x16 __attribute__((ext_vector_type(16)));

static __device__ __forceinline__ unsigned short f2bf(float x) {
  __hip_bfloat16 h = __float2bfloat16(x);
  return __builtin_bit_cast(unsigned short, h);
}

// ---------------- Kernel 1: normalize prototypes -> bf16, pre-swizzled slab-major ----------------
// Layout: byte(row r, slab s, local col c in [0,128)) = OFF_PN + s*131072 + r*128 + (c ^ ((r&7)<<4))
__global__ __launch_bounds__(256) void norm_protos_k(const float* __restrict__ protos,
                                                     unsigned char* __restrict__ ws) {
  const int w = threadIdx.x >> 6, lane = threadIdx.x & 63;
  const int r = blockIdx.x * 4 + w;                 // 256 blocks * 4 waves = 1024 rows
  const float4 v = ((const float4*)protos)[r * 64 + lane];
  float ss = v.x*v.x + v.y*v.y + v.z*v.z + v.w*v.w;
#pragma unroll
  for (int m = 1; m < 64; m <<= 1) ss += __shfl_xor(ss, m, 64);
  const float sc = 1.0f / fmaxf(sqrtf(ss), 1e-12f);
  uint2 p;
  p.x = (unsigned)f2bf(v.x * sc) | ((unsigned)f2bf(v.y * sc) << 16);
  p.y = (unsigned)f2bf(v.z * sc) | ((unsigned)f2bf(v.w * sc) << 16);
  const int s = lane >> 4;                               // slab = (lane*4)/64
  const int c = ((lane & 15) * 8) ^ ((r & 7) << 4);      // swizzled byte col within 128B
  *(uint2*)(ws + OFF_PN + s * 131072 + r * 128 + c) = p;
}

// ---------------- Kernel 2: compact selected (gt==1) query indices ----------------
__global__ __launch_bounds__(256) void compact_k(const int* __restrict__ gt,
                                                 unsigned char* __restrict__ ws) {
  const int idx = blockIdx.x * 256 + threadIdx.x;   // 128 blocks * 256 = 32768
  if (gt[idx] == 1) {
    int p = atomicAdd((int*)(ws + OFF_NSEL), 1);
    ((int*)(ws + OFF_SEL))[p] = idx;
  }
}

// ---------------- Kernel 3: fused normalize(Q) + GEMM + exp2/lse + pos-sum ----------------
__global__ __launch_bounds__(512, 2) void main_k(const float* __restrict__ lv,
                                                 unsigned char* __restrict__ ws) {
  __shared__ __align__(16) unsigned char Aq[128 * 512];  // queries bf16, swizzled [128 rows][512B]
  __shared__ __align__(16) unsigned char Ps[512 * 128];  // proto slab [512 rows][128B]; reused for reduction
  __shared__ int   kq[128];
  __shared__ float partsum[2];

  const int b    = blockIdx.x;
  const int tid  = threadIdx.x;
  const int w    = tid >> 6;          // wave id 0..7 == proto-row group
  const int lane = tid & 63;
  const int hi   = lane >> 5;
  const int l31  = lane & 31;

  float* partials = (float*)(ws + OFF_PART);
  const int n_sel = *(const volatile int*)(ws + OFF_NSEL);
  const int base  = b * 128;
  if (base >= n_sel) { if (tid == 0) partials[b] = 0.0f; return; }
  const int* sel = (const int*)(ws + OFF_SEL);

  // ---- Phase 1: load + L2-normalize 128 query rows -> bf16 LDS (swizzled) ----
  for (int i = 0; i < 16; ++i) {
    const int j    = w * 16 + i;
    const int slot = base + j;
    const int qi   = (slot < n_sel) ? sel[slot] : sel[base];  // pad with a valid row
    const float4 v = ((const float4*)lv)[qi * 64 + lane];
    float ss = v.x*v.x + v.y*v.y + v.z*v.z + v.w*v.w;
#pragma unroll
    for (int m = 1; m < 64; m <<= 1) ss += __shfl_xor(ss, m, 64);
    const float sc = 1.0f / fmaxf(sqrtf(ss), 1e-12f);
    uint2 p;
    p.x = (unsigned)f2bf(v.x * sc) | ((unsigned)f2bf(v.y * sc) << 16);
    p.y = (unsigned)f2bf(v.z * sc) | ((unsigned)f2bf(v.w * sc) << 16);
    *(uint2*)(Aq + j * 512 + ((lane * 8) ^ ((j & 7) << 4))) = p;
    if (lane == 0) kq[j] = qi & (KC - 1);
  }
  __syncthreads();

  int kqr[4];
#pragma unroll
  for (int j = 0; j < 4; ++j) kqr[j] = kq[j * 32 + l31];

  float l_acc[4] = {0.f, 0.f, 0.f, 0.f};
  float p_acc[4] = {0.f, 0.f, 0.f, 0.f};

  // ---- P loop: 2 chunks of 512 protos, each staged as 4 d-slabs of 64 ----
  for (int c = 0; c < 2; ++c) {
    f32x16 acc[2][4];
#pragma unroll
    for (int i = 0; i < 2; ++i)
#pragma unroll
      for (int j = 0; j < 4; ++j)
#pragma unroll
        for (int t = 0; t < 16; ++t) acc[i][j][t] = 0.0f;

    for (int s = 0; s < 4; ++s) {
      __syncthreads();  // previous slab fully consumed
      const unsigned char* gsrc = ws + OFF_PN + s * 131072 + c * 65536;
#pragma unroll
      for (int i = 0; i < 8; ++i) {
        const int o = i * 8192 + tid * 16;
        *(uint4*)(Ps + o) = *(const uint4*)(gsrc + o);   // linear copy (data pre-swizzled)
      }
      __syncthreads();

#pragma unroll
      for (int k = 0; k < 4; ++k) {   // 4 K-steps of 16 within the 64-d slab
        const int arow = w * 64 + l31;
        const int acol = (k * 32 + hi * 16) ^ ((l31 & 7) << 4);
        const bf16x8 a0 = *(const bf16x8*)(Ps + arow * 128 + acol);
        const bf16x8 a1 = *(const bf16x8*)(Ps + (arow + 32) * 128 + acol);
        bf16x8 bv[4];
#pragma unroll
        for (int j = 0; j < 4; ++j) {
          const int q = j * 32 + l31;
          const int bcol = (s * 128 + k * 32 + hi * 16) ^ ((q & 7) << 4);
          bv[j] = *(const bf16x8*)(Aq + q * 512 + bcol);
        }
#pragma unroll
        for (int j = 0; j < 4; ++j) {
          acc[0][j] = __builtin_amdgcn_mfma_f32_32x32x16_bf16(a0, bv[j], acc[0][j], 0, 0, 0);
          acc[1][j] = __builtin_amdgcn_mfma_f32_32x32x16_bf16(a1, bv[j], acc[1][j], 0, 0, 0);
        }
      }
    }

    // ---- epilogue for this chunk: y = sim*10*log2e; l += 2^y; pos += y if row>>2==k ----
#pragma unroll
    for (int i = 0; i < 2; ++i) {
      const int base_r4 = c * 128 + w * 16 + i * 8 + hi;  // (global proto row base)/4
#pragma unroll
      for (int j = 0; j < 4; ++j) {
#pragma unroll
        for (int g = 0; g < 4; ++g) {
          const float pm = (base_r4 + 2 * g == kqr[j]) ? 1.0f : 0.0f;
#pragma unroll
          for (int t = 0; t < 4; ++t) {
            const float y = acc[i][j][g * 4 + t] * C10L2E;
            l_acc[j] += exp2f(y);
            p_acc[j] = fmaf(pm, y, p_acc[j]);
          }
        }
      }
    }
  }

  // combine the two row-half lanes (lane ^ 32)
#pragma unroll
  for (int j = 0; j < 4; ++j) {
    l_acc[j] += __shfl_xor(l_acc[j], 32, 64);
    p_acc[j] += __shfl_xor(p_acc[j], 32, 64);
  }

  __syncthreads();                       // done reading Ps -> reuse as reduction buffers
  float* red_l = (float*)Ps;             // [8][128]
  float* red_p = (float*)(Ps + 4096);    // [8][128]
  if (hi == 0) {
#pragma unroll
    for (int j = 0; j < 4; ++j) {
      red_l[w * 128 + j * 32 + l31] = l_acc[j];
      red_p[w * 128 + j * 32 + l31] = p_acc[j];
    }
  }
  __syncthreads();

  float contrib = 0.0f;
  if (tid < 128) {
    float L = 0.0f, P = 0.0f;
#pragma unroll
    for (int ww = 0; ww < 8; ++ww) { L += red_l[ww * 128 + tid]; P += red_p[ww * 128 + tid]; }
    contrib = (base + tid < n_sel) ? LN2F * (4.0f * log2f(L) - P) : 0.0f;
  }
#pragma unroll
  for (int m = 1; m < 64; m <<= 1) contrib += __shfl_xor(contrib, m, 64);
  if (tid < 128 && lane == 0) partsum[w] = contrib;
  __syncthreads();
  if (tid == 0) partials[b] = partsum[0] + partsum[1];
}

// ---------------- Kernel 4: final reduce + divide ----------------
__global__ __launch_bounds__(256) void finish_k(const unsigned char* __restrict__ ws,
                                                float* __restrict__ out) {
  __shared__ float accs[4];
  const int tid = threadIdx.x;
  float v = ((const float*)(ws + OFF_PART))[tid];
#pragma unroll
  for (int m = 1; m < 64; m <<= 1) v += __shfl_xor(v, m, 64);
  if ((tid & 63) == 0) accs[tid >> 6] = v;
  __syncthreads();
  if (tid == 0) {
    const float total = accs[0] + accs[1] + accs[2] + accs[3];
    const int n = *(const int*)(ws + OFF_NSEL);
    out[0] = (n > 0) ? total / fmaxf(4.0f * (float)n, 1.0f) : 0.0f;
  }
}

extern "C" void kernel_launch(void* const* d_in, const int* in_sizes, int n_in,
                              void* d_out, int out_size, void* d_ws, size_t ws_size,
                              hipStream_t stream) {
  const float* lv     = (const float*)d_in[0];   // (128,256,256) f32
  const float* protos = (const float*)d_in[1];   // (1024,256,1,1) f32
  const int*   gt     = (const int*)d_in[2];     // (128,256) i32
  (void)in_sizes; (void)n_in; (void)out_size; (void)ws_size;
  unsigned char* ws = (unsigned char*)d_ws;

  hipMemsetAsync(d_ws, 0, 256, stream);                      // zero n_sel
  norm_protos_k<<<256, 256, 0, stream>>>(protos, ws);
  compact_k<<<128, 256, 0, stream>>>(gt, ws);
  main_k<<<256, 512, 0, stream>>>(lv, ws);
  finish_k<<<1, 256, 0, stream>>>(ws, (float*)d_out);
}

// Round 2
// 47.443 us; speedup vs baseline: 1.5126x; 1.5126x over previous
//
#include <hip/hip_runtime.h>
#include <hip/hip_bf16.h>
#include <stdint.h>

// Problem constants (fixed by setup_inputs)
#define KC   256      // concepts
#define BB   128      // batch
#define DD   256      // feature dim
#define MM   4        // protos per concept
#define NPROT 1024    // KC*MM
#define NQ   32768    // BB*KC

// ws layout (bytes), total ~0.92 MB
#define OFF_NSEL 0                         // int
#define OFF_TOT  8                         // float
#define OFF_SEL  256                       // int[32768] (128 KB)
#define OFF_PN   132096                    // bf16 protos, k-major: [16 kslabs][1024 rows][32B]  (512 KB)
#define OFF_ACC  (132096 + 16*1024*32)     // float2[32768] per-query {expsum, possum} (256 KB)

#define LN2F    0.69314718055994531f
#define C10L2E  14.426950408889634f        // 10 * log2(e): folds 1/T into exp2 domain

typedef __bf16 bf16x8 __attribute__((ext_vector_type(8)));
typedef float  f32x16 __attribute__((ext_vector_type(16)));

static __device__ __forceinline__ unsigned short f2bf(float x) {
  __hip_bfloat16 h = __float2bfloat16(x);
  return __builtin_bit_cast(unsigned short, h);
}

// ---------------- Kernel 1: normalize protos -> bf16 k-major layout; zero accumulators ----------------
// layout: byte(row r, k-slab s, sub-byte c in [0,32)) = OFF_PN + s*32768 + r*32 + c
__global__ __launch_bounds__(256) void norm_protos_k(const float* __restrict__ protos,
                                                     unsigned char* __restrict__ ws) {
  const int gtid = blockIdx.x * 256 + threadIdx.x;   // 65536 threads
  ((float*)(ws + OFF_ACC))[gtid] = 0.0f;             // zero 256 KB accum
  if (gtid == 0) { *(int*)(ws + OFF_NSEL) = 0; *(float*)(ws + OFF_TOT) = 0.0f; }

  const int w = threadIdx.x >> 6, lane = threadIdx.x & 63;
  const int r = blockIdx.x * 4 + w;                  // 1024 rows
  const float4 v = ((const float4*)protos)[r * 64 + lane];
  float ss = v.x*v.x + v.y*v.y + v.z*v.z + v.w*v.w;
#pragma unroll
  for (int m = 1; m < 64; m <<= 1) ss += __shfl_xor(ss, m, 64);
  const float sc = 1.0f / fmaxf(sqrtf(ss), 1e-12f);
  uint2 p;
  p.x = (unsigned)f2bf(v.x * sc) | ((unsigned)f2bf(v.y * sc) << 16);
  p.y = (unsigned)f2bf(v.z * sc) | ((unsigned)f2bf(v.w * sc) << 16);
  // element d = lane*4 .. +3 -> k-slab = lane>>2, byte in slab = (lane&3)*8
  *(uint2*)(ws + OFF_PN + (lane >> 2) * 32768 + r * 32 + (lane & 3) * 8) = p;
}

// ---------------- Kernel 2: compact selected (gt==1) query indices ----------------
__global__ __launch_bounds__(256) void compact_k(const int* __restrict__ gt,
                                                 unsigned char* __restrict__ ws) {
  const int idx = blockIdx.x * 256 + threadIdx.x;    // 128 blocks * 256 = 32768
  if (gt[idx] == 1) {
    int p = atomicAdd((int*)(ws + OFF_NSEL), 1);
    ((int*)(ws + OFF_SEL))[p] = idx;
  }
}

// ---------------- Kernel 3: fused normalize(Q) + GEMM(direct-L2 A-frags) + exp2 partials ----------------
// grid: 512 tiles (64 queries each) x 4 proto-chunks (256 rows each) = 2048 blocks, 256 threads
__global__ __launch_bounds__(256, 4) void main_k(const float* __restrict__ lv,
                                                 unsigned char* __restrict__ ws) {
  __shared__ __align__(16) unsigned char Aq[64 * 512];  // 64 query rows, bf16, swizzled
  __shared__ int qis[64];

  const int tid  = threadIdx.x;
  const int w    = tid >> 6;        // wave 0..3
  const int lane = tid & 63;
  const int hi   = lane >> 5;
  const int l31  = lane & 31;

  const int n_sel = *(const int*)(ws + OFF_NSEL);
  const int tile  = blockIdx.x >> 2;
  const int c     = blockIdx.x & 3;          // proto chunk
  const int base  = tile * 64;
  if (base >= n_sel) return;
  const int* sel = (const int*)(ws + OFF_SEL);

  // ---- Phase 1: normalize 64 query rows; 16-lane group per row, 4 rows/group ----
  const int grp = tid >> 4, sub = tid & 15;
#pragma unroll
  for (int t = 0; t < 4; ++t) {
    const int j    = grp * 4 + t;
    const int slot = base + j;
    const int valid = slot < n_sel;
    const int qi   = valid ? sel[slot] : sel[base];
    float4 vv[4];
#pragma unroll
    for (int u = 0; u < 4; ++u) vv[u] = ((const float4*)lv)[qi * 64 + u * 16 + sub];
    float ss = 0.0f;
#pragma unroll
    for (int u = 0; u < 4; ++u)
      ss += vv[u].x*vv[u].x + vv[u].y*vv[u].y + vv[u].z*vv[u].z + vv[u].w*vv[u].w;
#pragma unroll
    for (int m = 1; m < 16; m <<= 1) ss += __shfl_xor(ss, m, 64);
    const float sc = 1.0f / fmaxf(sqrtf(ss), 1e-12f);
#pragma unroll
    for (int u = 0; u < 4; ++u) {
      uint2 p;
      p.x = (unsigned)f2bf(vv[u].x * sc) | ((unsigned)f2bf(vv[u].y * sc) << 16);
      p.y = (unsigned)f2bf(vv[u].z * sc) | ((unsigned)f2bf(vv[u].w * sc) << 16);
      *(uint2*)(Aq + j * 512 + ((u * 128 + sub * 8) ^ ((j & 7) << 4))) = p;
    }
    if (sub == 0) qis[j] = valid ? qi : -1;
  }
  __syncthreads();

  int kqr[2];
#pragma unroll
  for (int j = 0; j < 2; ++j) {
    const int q = qis[j * 32 + l31];
    kqr[j] = (q >= 0) ? (q & (KC - 1)) : -1;
  }

  f32x16 acc[2][2];
#pragma unroll
  for (int i = 0; i < 2; ++i)
#pragma unroll
    for (int j = 0; j < 2; ++j)
#pragma unroll
      for (int t = 0; t < 16; ++t) acc[i][j][t] = 0.0f;

  // ---- K loop: A-frags direct from L2-resident k-major proto slab ----
  const unsigned char* pn = ws + OFF_PN + (c * 256 + w * 64 + l31) * 32 + hi * 16;
  const int bcolbase = hi * 16;
#pragma unroll 4
  for (int k = 0; k < 16; ++k) {
    const bf16x8 a0 = *(const bf16x8*)(pn + k * 32768);
    const bf16x8 a1 = *(const bf16x8*)(pn + k * 32768 + 1024);   // +32 rows
    const int bc = (k * 32 + bcolbase) ^ ((l31 & 7) << 4);
    const bf16x8 b0 = *(const bf16x8*)(Aq + l31 * 512 + bc);
    const bf16x8 b1 = *(const bf16x8*)(Aq + (32 + l31) * 512 + bc);
    acc[0][0] = __builtin_amdgcn_mfma_f32_32x32x16_bf16(a0, b0, acc[0][0], 0, 0, 0);
    acc[0][1] = __builtin_amdgcn_mfma_f32_32x32x16_bf16(a0, b1, acc[0][1], 0, 0, 0);
    acc[1][0] = __builtin_amdgcn_mfma_f32_32x32x16_bf16(a1, b0, acc[1][0], 0, 0, 0);
    acc[1][1] = __builtin_amdgcn_mfma_f32_32x32x16_bf16(a1, b1, acc[1][1], 0, 0, 0);
  }

  // ---- epilogue: y = sim*10*log2e; L += 2^y; P += y on positives ----
  float l_acc[2] = {0.f, 0.f}, p_acc[2] = {0.f, 0.f};
  const int r4base = c * 64 + w * 16 + hi;   // row>>2 = r4base + i*8 + 2*g
#pragma unroll
  for (int i = 0; i < 2; ++i)
#pragma unroll
    for (int j = 0; j < 2; ++j)
#pragma unroll
      for (int g = 0; g < 4; ++g) {
        const float pm = (r4base + i * 8 + 2 * g == kqr[j]) ? 1.0f : 0.0f;
#pragma unroll
        for (int t = 0; t < 4; ++t) {
          const float y = acc[i][j][g * 4 + t] * C10L2E;
          l_acc[j] += __builtin_amdgcn_exp2f(y);
          p_acc[j] = fmaf(pm, y, p_acc[j]);
        }
      }

#pragma unroll
  for (int j = 0; j < 2; ++j) {
    l_acc[j] += __shfl_xor(l_acc[j], 32, 64);
    p_acc[j] += __shfl_xor(p_acc[j], 32, 64);
  }

  if (hi == 0) {
    float* accb = (float*)(ws + OFF_ACC);
#pragma unroll
    for (int j = 0; j < 2; ++j) {
      const int q = qis[j * 32 + l31];
      if (q >= 0) {
        atomicAdd(accb + q * 2,     l_acc[j]);
        atomicAdd(accb + q * 2 + 1, p_acc[j]);
      }
    }
  }
}

// ---------------- Kernel 4: per-query contribution + grid sum into ws total ----------------
__global__ __launch_bounds__(256) void finish1_k(const int* __restrict__ gt,
                                                 unsigned char* __restrict__ ws) {
  __shared__ float accs[4];
  const int i = blockIdx.x * 256 + threadIdx.x;   // 128 blocks -> 32768
  float contrib = 0.0f;
  if (gt[i] == 1) {
    const float* accb = (const float*)(ws + OFF_ACC);
    const float L = accb[i * 2], P = accb[i * 2 + 1];
    contrib = LN2F * (4.0f * __builtin_amdgcn_logf(L) - P);
  }
#pragma unroll
  for (int m = 1; m < 64; m <<= 1) contrib += __shfl_xor(contrib, m, 64);
  if ((threadIdx.x & 63) == 0) accs[threadIdx.x >> 6] = contrib;
  __syncthreads();
  if (threadIdx.x == 0)
    atomicAdd((float*)(ws + OFF_TOT), accs[0] + accs[1] + accs[2] + accs[3]);
}

// ---------------- Kernel 5: final divide ----------------
__global__ __launch_bounds__(64) void finish2_k(const unsigned char* __restrict__ ws,
                                                float* __restrict__ out) {
  if (threadIdx.x == 0) {
    const int n = *(const int*)(ws + OFF_NSEL);
    const float total = *(const float*)(ws + OFF_TOT);
    out[0] = (n > 0) ? total / (4.0f * (float)n) : 0.0f;
  }
}

extern "C" void kernel_launch(void* const* d_in, const int* in_sizes, int n_in,
                              void* d_out, int out_size, void* d_ws, size_t ws_size,
                              hipStream_t stream) {
  const float* lv     = (const float*)d_in[0];   // (128,256,256) f32
  const float* protos = (const float*)d_in[1];   // (1024,256,1,1) f32
  const int*   gt     = (const int*)d_in[2];     // (128,256) i32
  (void)in_sizes; (void)n_in; (void)out_size; (void)ws_size;
  unsigned char* ws = (unsigned char*)d_ws;

  norm_protos_k<<<256, 256, 0, stream>>>(protos, ws);
  compact_k<<<128, 256, 0, stream>>>(gt, ws);
  main_k<<<2048, 256, 0, stream>>>(lv, ws);
  finish1_k<<<128, 256, 0, stream>>>(gt, ws);
  finish2_k<<<1, 64, 0, stream>>>(ws, (float*)d_out);
}

// Round 4
// 46.645 us; speedup vs baseline: 1.5385x; 1.0171x over previous
//
#include <hip/hip_runtime.h>
#include <hip/hip_bf16.h>
#include <stdint.h>

// Problem constants (fixed by setup_inputs)
#define KC   256      // concepts
#define DD   256      // feature dim
#define NPROT 1024    // KC*M
#define NQ   32768    // B*KC

// ws layout (bytes), total 917760 B (~0.92 MB, proven in round 2)
#define OFF_NSEL 0                        // int
#define OFF_TOT  8                        // float
#define OFF_SEL  256                      // int[32768] (128 KB)
#define OFF_PN   131328                   // bf16 protos k-major: [16 kslabs][1024 rows][32B] (512 KB)
#define OFF_ACC  655616                   // float2[32768] per-query {expsum, possum} (256 KB)

#define LN2F    0.69314718055994531f
#define C10L2E  14.426950408889634f       // 10 * log2(e): folds 1/T into exp2 domain

typedef __bf16 bf16x8 __attribute__((ext_vector_type(8)));
typedef float  f32x16 __attribute__((ext_vector_type(16)));

static __device__ __forceinline__ unsigned short f2bf(float x) {
  __hip_bfloat16 h = __float2bfloat16(x);
  return __builtin_bit_cast(unsigned short, h);
}

// ---------------- Kernel 1: zero counters/ACC + normalize protos -> bf16 k-major ----------------
__global__ __launch_bounds__(256) void prep_k(const float* __restrict__ protos,
                                              unsigned char* __restrict__ ws) {
  const int gtid = blockIdx.x * 256 + threadIdx.x;   // 65536 threads
  ((float*)(ws + OFF_ACC))[gtid] = 0.0f;             // zero 256 KB accum
  if (gtid == 0) { *(int*)(ws + OFF_NSEL) = 0; *(float*)(ws + OFF_TOT) = 0.0f; }

  const int w = threadIdx.x >> 6, lane = threadIdx.x & 63;
  const int r = blockIdx.x * 4 + w;                  // 256 blocks * 4 = 1024 rows
  const float4 v = ((const float4*)protos)[r * 64 + lane];
  float ss = v.x*v.x + v.y*v.y + v.z*v.z + v.w*v.w;
#pragma unroll
  for (int m = 1; m < 64; m <<= 1) ss += __shfl_xor(ss, m, 64);
  const float sc = 1.0f / fmaxf(sqrtf(ss), 1e-12f);
  uint2 p;
  p.x = (unsigned)f2bf(v.x * sc) | ((unsigned)f2bf(v.y * sc) << 16);
  p.y = (unsigned)f2bf(v.z * sc) | ((unsigned)f2bf(v.w * sc) << 16);
  // element d = lane*4.. -> k-slab = lane>>2, byte in slab-row = (lane&3)*8
  *(uint2*)(ws + OFF_PN + (lane >> 2) * 32768 + r * 32 + (lane & 3) * 8) = p;
}

// ---------------- Kernel 2: compact selected (gt==1) query indices ----------------
__global__ __launch_bounds__(256) void compact_k(const int* __restrict__ gt,
                                                 unsigned char* __restrict__ ws) {
  const int idx = blockIdx.x * 256 + threadIdx.x;    // 128 blocks * 256 = 32768
  if (gt[idx] == 1) {
    int p = atomicAdd((int*)(ws + OFF_NSEL), 1);
    ((int*)(ws + OFF_SEL))[p] = idx;
  }
}

// ---------------- Kernel 3: fused normalize(Q) + GEMM (two half-passes, depth-4 A-pipeline) ----------------
// grid: 512 tiles (64 queries) x 4 chunks (256 protos) = 2048 blocks, 256 threads
__global__ __launch_bounds__(256, 4) void main_k(const float* __restrict__ lv,
                                                 unsigned char* __restrict__ ws) {
  __shared__ __align__(16) unsigned char Aq[64 * 512];  // 64 query rows, bf16, swizzled (32 KB)

  const int tid  = threadIdx.x;
  const int w    = tid >> 6;        // wave 0..3
  const int lane = tid & 63;
  const int hi   = lane >> 5;
  const int l31  = lane & 31;

  const int n_sel = *(const int*)(ws + OFF_NSEL);
  const int tile  = blockIdx.x >> 2;
  const int c     = blockIdx.x & 3;          // proto chunk
  const int base  = tile * 64;
  if (base >= n_sel) return;
  const int* sel = (const int*)(ws + OFF_SEL);

  // per-lane query ids for the epilogue (issued before barrier; L2-hot)
  int qv[2], kqr[2];
#pragma unroll
  for (int j = 0; j < 2; ++j) {
    const int slot = base + j * 32 + l31;
    const int valid = slot < n_sel;
    const int q = valid ? sel[slot] : sel[base];
    qv[j]  = valid ? q : -1;
    kqr[j] = valid ? (q & (KC - 1)) : -1;
  }

  // A-fragment base pointers for the two half-passes (32 rows each)
  const unsigned char* pn0 = ws + OFF_PN + (c * 256 + w * 64 + l31) * 32 + hi * 16;
  const unsigned char* pn1 = pn0 + 32 * 32;  // +32 rows

  // depth-4 prefetch of half-0 A-frags, issued BEFORE the barrier
  bf16x8 pa[4];
#pragma unroll
  for (int p = 0; p < 4; ++p) pa[p] = *(const bf16x8*)(pn0 + p * 32768);

  // ---- Phase 1: normalize 64 query rows; 16-lane group per row, 4 rows/group ----
  const int grp = tid >> 4, sub = tid & 15;
#pragma unroll
  for (int t = 0; t < 4; ++t) {
    const int j    = grp * 4 + t;
    const int slot = base + j;
    const int qi   = (slot < n_sel) ? sel[slot] : sel[base];
    float4 vv[4];
#pragma unroll
    for (int u = 0; u < 4; ++u) vv[u] = ((const float4*)lv)[qi * 64 + u * 16 + sub];
    float ss = 0.0f;
#pragma unroll
    for (int u = 0; u < 4; ++u)
      ss += vv[u].x*vv[u].x + vv[u].y*vv[u].y + vv[u].z*vv[u].z + vv[u].w*vv[u].w;
#pragma unroll
    for (int m = 1; m < 16; m <<= 1) ss += __shfl_xor(ss, m, 64);
    const float sc = 1.0f / fmaxf(sqrtf(ss), 1e-12f);
    const int swz = ((j & 7) << 4) ^ (((j >> 3) & 3) << 7);  // full 512B spread
#pragma unroll
    for (int u = 0; u < 4; ++u) {
      uint2 p;
      p.x = (unsigned)f2bf(vv[u].x * sc) | ((unsigned)f2bf(vv[u].y * sc) << 16);
      p.y = (unsigned)f2bf(vv[u].z * sc) | ((unsigned)f2bf(vv[u].w * sc) << 16);
      *(uint2*)(Aq + j * 512 + ((u * 128 + sub * 8) ^ swz)) = p;
    }
  }
  __syncthreads();

  float l_acc[2], p_acc[2];
  const int bswz = ((l31 & 7) << 4) ^ (((l31 >> 3) & 3) << 7);  // same for rows l31 and 32+l31

#pragma unroll
  for (int h = 0; h < 2; ++h) {
    const unsigned char* pnh  = (h == 0) ? pn0 : pn1;
    f32x16 acc0, acc1;
#pragma unroll
    for (int t = 0; t < 16; ++t) { acc0[t] = 0.0f; acc1[t] = 0.0f; }

#pragma unroll
    for (int k = 0; k < 16; ++k) {
      const bf16x8 a = pa[k & 3];
      if (k < 12)       pa[k & 3] = *(const bf16x8*)(pnh + (k + 4) * 32768);
      else if (h == 0)  pa[k & 3] = *(const bf16x8*)(pn1 + (k - 12) * 32768);
      const int bc = (k * 32 + hi * 16) ^ bswz;
      const bf16x8 b0 = *(const bf16x8*)(Aq + l31 * 512 + bc);
      const bf16x8 b1 = *(const bf16x8*)(Aq + (32 + l31) * 512 + bc);
      acc0 = __builtin_amdgcn_mfma_f32_32x32x16_bf16(a, b0, acc0, 0, 0, 0);
      acc1 = __builtin_amdgcn_mfma_f32_32x32x16_bf16(a, b1, acc1, 0, 0, 0);
    }

    // ---- epilogue for half h: y = sim*10*log2e; L += 2^y; P += y on positives ----
    const int r4base = c * 64 + w * 16 + h * 8 + hi;   // row>>2 = r4base + 2*g
#pragma unroll
    for (int j = 0; j < 2; ++j) {
      float l4[4] = {0.f, 0.f, 0.f, 0.f};
      float p4[4] = {0.f, 0.f, 0.f, 0.f};
#pragma unroll
      for (int g = 0; g < 4; ++g) {
        const float pm = (r4base + 2 * g == kqr[j]) ? 1.0f : 0.0f;
#pragma unroll
        for (int t = 0; t < 4; ++t) {
          const float y = ((j == 0) ? acc0[g * 4 + t] : acc1[g * 4 + t]) * C10L2E;
          l4[t] += __builtin_amdgcn_exp2f(y);
          p4[t] = fmaf(pm, y, p4[t]);
        }
      }
      const float ls = (l4[0] + l4[1]) + (l4[2] + l4[3]);
      const float ps = (p4[0] + p4[1]) + (p4[2] + p4[3]);
      if (h == 0) { l_acc[j] = ls;  p_acc[j] = ps; }
      else        { l_acc[j] += ls; p_acc[j] += ps; }
    }
  }

  // combine the two row-half lanes (lane ^ 32), then one atomic pair per query
#pragma unroll
  for (int j = 0; j < 2; ++j) {
    l_acc[j] += __shfl_xor(l_acc[j], 32, 64);
    p_acc[j] += __shfl_xor(p_acc[j], 32, 64);
  }
  if (hi == 0) {
    float* accb = (float*)(ws + OFF_ACC);
#pragma unroll
    for (int j = 0; j < 2; ++j) {
      if (qv[j] >= 0) {
        atomicAdd(accb + qv[j] * 2,     l_acc[j]);
        atomicAdd(accb + qv[j] * 2 + 1, p_acc[j]);
      }
    }
  }
}

// ---------------- Kernel 4: per-query contribution + grid sum into ws total ----------------
__global__ __launch_bounds__(256) void finish1_k(const int* __restrict__ gt,
                                                 unsigned char* __restrict__ ws) {
  __shared__ float accs[4];
  const int i = blockIdx.x * 256 + threadIdx.x;   // 128 blocks -> 32768
  float contrib = 0.0f;
  if (gt[i] == 1) {
    const float* accb = (const float*)(ws + OFF_ACC);
    const float L = accb[i * 2], P = accb[i * 2 + 1];
    contrib = LN2F * (4.0f * __builtin_amdgcn_logf(L) - P);
  }
#pragma unroll
  for (int m = 1; m < 64; m <<= 1) contrib += __shfl_xor(contrib, m, 64);
  if ((threadIdx.x & 63) == 0) accs[threadIdx.x >> 6] = contrib;
  __syncthreads();
  if (threadIdx.x == 0)
    atomicAdd((float*)(ws + OFF_TOT), accs[0] + accs[1] + accs[2] + accs[3]);
}

// ---------------- Kernel 5: final divide ----------------
__global__ __launch_bounds__(64) void finish2_k(const unsigned char* __restrict__ ws,
                                                float* __restrict__ out) {
  if (threadIdx.x == 0) {
    const int n = *(const int*)(ws + OFF_NSEL);
    const float total = *(const float*)(ws + OFF_TOT);
    out[0] = (n > 0) ? total / (4.0f * (float)n) : 0.0f;
  }
}

extern "C" void kernel_launch(void* const* d_in, const int* in_sizes, int n_in,
                              void* d_out, int out_size, void* d_ws, size_t ws_size,
                              hipStream_t stream) {
  const float* lv     = (const float*)d_in[0];   // (128,256,256) f32
  const float* protos = (const float*)d_in[1];   // (1024,256,1,1) f32
  const int*   gt     = (const int*)d_in[2];     // (128,256) i32
  (void)in_sizes; (void)n_in; (void)out_size; (void)ws_size;
  unsigned char* ws = (unsigned char*)d_ws;

  prep_k<<<256, 256, 0, stream>>>(protos, ws);
  compact_k<<<128, 256, 0, stream>>>(gt, ws);
  main_k<<<2048, 256, 0, stream>>>(lv, ws);
  finish1_k<<<128, 256, 0, stream>>>(gt, ws);
  finish2_k<<<1, 64, 0, stream>>>(ws, (float*)d_out);
}